// Round 4
// baseline (115.569 us; speedup 1.0000x reference)
//
#include <hip/hip_runtime.h>

typedef __attribute__((ext_vector_type(8))) short bf16x8;
typedef __attribute__((ext_vector_type(4))) float f32x4;

#define DEVI static __device__ __forceinline__

namespace {
constexpr int NSEQ = 2048, NH = 16;
constexpr int D = 1024, D3 = 3072;
}

DEVI unsigned short f2bf(float f) {
  union { float f; unsigned int u; } v; v.f = f;
  unsigned int r = v.u + 0x7FFFu + ((v.u >> 16) & 1u);
  return (unsigned short)(r >> 16);
}

DEVI void gload16(const unsigned short* g, unsigned short* lds) {
  __builtin_amdgcn_global_load_lds(
      (const __attribute__((address_space(1))) unsigned int*)g,
      (__attribute__((address_space(3))) unsigned int*)lds, 16, 0, 0);
}

DEVI f32x4 mfma16(bf16x8 a, bf16x8 b, f32x4 c) {
  return __builtin_amdgcn_mfma_f32_16x16x32_bf16(a, b, c, 0, 0, 0);
}

DEVI float exp2g(float x) {
#if __has_builtin(__builtin_amdgcn_exp2f)
  return __builtin_amdgcn_exp2f(x);
#else
  return exp2f(x);
#endif
}

DEVI unsigned int cvtpk(float a, float b) {
  unsigned int r;
  asm("v_cvt_pk_bf16_f32 %0, %1, %2" : "=v"(r) : "v"(a), "v"(b));
  return r;
}

// ---------------- prep: cast x -> bf16  +  transpose/cast W -> Wt ----------
__global__ __launch_bounds__(256) void prep_k(const float* __restrict__ x,
                                              const float* __restrict__ W,
                                              unsigned short* __restrict__ xb,
                                              unsigned short* __restrict__ Wt) {
  __shared__ float t[32][33];
  const int bid = blockIdx.x;
  if (bid < 4096) {
    int i = (bid * 256 + threadIdx.x) * 4;
    float4 v = *reinterpret_cast<const float4*>(x + i);
    ushort4 o;
    o.x = f2bf(v.x); o.y = f2bf(v.y); o.z = f2bf(v.z); o.w = f2bf(v.w);
    *reinterpret_cast<ushort4*>(xb + i) = o;
  } else {
    const int b2 = bid - 4096;
    const int c0 = (b2 % 96) * 32, k0 = (b2 / 96) * 32;
    const int tx = threadIdx.x & 31, ty = threadIdx.x >> 5;  // ty 0..7
#pragma unroll
    for (int r = 0; r < 32; r += 8)
      t[ty + r][tx] = W[(size_t)(k0 + ty + r) * D3 + c0 + tx];
    __syncthreads();
#pragma unroll
    for (int r = 0; r < 32; r += 8)
      Wt[(size_t)(c0 + ty + r) * D + k0 + tx] = f2bf(t[tx][ty + r]);
  }
}

// ---------------- QKV GEMM: [4096x1024] x [1024x3072], 256^2 8-phase ------
// 512 thr = 8 waves (2M x 4N), BK=64, LDS 128 KiB (2 dbuf x 2 half x A,B).
// Per phase: {ds-read frag subtile | stage 1 half-tile | s_barrier |
// lgkmcnt(0) | setprio(1) 16xMFMA setprio(0) | s_barrier}; counted vmcnt(2)
// only at phases 4 and 8. Chunk-XOR (c ^ (r&7)) LDS swizzle applied on both
// the pre-swizzled global source and the frag reads.
// Epilogue scatters: Q*(0.125*log2e), K -> [B,H,N,64], V^T -> [B,H,64,N].
__global__ __launch_bounds__(512, 2) void qkv_gemm_k(const unsigned short* __restrict__ xb,
                                                     const unsigned short* __restrict__ Wt,
                                                     unsigned short* __restrict__ qw,
                                                     unsigned short* __restrict__ kw,
                                                     unsigned short* __restrict__ vtw) {
  __shared__ unsigned short smA[2][2][128 * 64];
  __shared__ unsigned short smB[2][2][128 * 64];
  const int tid = threadIdx.x, w = tid >> 6, l = tid & 63;
  const int wm = w >> 2, wn = w & 3;          // wave grid 2 x 4
  const int g = l >> 4, ql = l & 15;
  const int m0 = blockIdx.x * 256, n0 = blockIdx.y * 256;

  // frag-read lane offsets (ushort units): r*64 + ((ks*4+g)^(ql&7))*8
  const int laneF0 = ql * 64 + ((g ^ (ql & 7)) << 3);
  const int laneF1 = ql * 64 + (((4 + g) ^ (ql & 7)) << 3);

  // staging: thread covers chunks (r=tid>>3, c) and (r+64, c), c pre-swizzled
  const int sr = tid >> 3;
  const int sc = (tid & 7) ^ (sr & 7);
  const unsigned short* gA = xb + (size_t)(m0 + sr) * D + sc * 8;
  const unsigned short* gB = Wt + (size_t)(n0 + sr) * D + sc * 8;
  const int w512 = w * 512;

  f32x4 acc[8][4];
#pragma unroll
  for (int i = 0; i < 8; ++i)
#pragma unroll
    for (int j = 0; j < 4; ++j) acc[i][j] = (f32x4){0.f, 0.f, 0.f, 0.f};

  bf16x8 af[4][2], bf0[2][2], bf1[2][2];

#define RDA(db, mh)                                                            \
  do {                                                                         \
    _Pragma("unroll") for (int i_ = 0; i_ < 4; ++i_) {                         \
      af[i_][0] = *(const bf16x8*)&smA[db][wm][((mh)*4 + i_) * 1024 + laneF0]; \
      af[i_][1] = *(const bf16x8*)&smA[db][wm][((mh)*4 + i_) * 1024 + laneF1]; \
    }                                                                          \
  } while (0)
#define RDB(db, nh, BF)                                                        \
  do {                                                                         \
    _Pragma("unroll") for (int i_ = 0; i_ < 2; ++i_) {                         \
      BF[i_][0] = *(const bf16x8*)&smB[db][wn >> 1][(wn & 1) * 4096 +          \
                                                    ((nh)*2 + i_) * 1024 + laneF0]; \
      BF[i_][1] = *(const bf16x8*)&smB[db][wn >> 1][(wn & 1) * 4096 +          \
                                                    ((nh)*2 + i_) * 1024 + laneF1]; \
    }                                                                          \
  } while (0)
#define QUAD(mh, nh, BF)                                                       \
  do {                                                                         \
    _Pragma("unroll") for (int i_ = 0; i_ < 4; ++i_)                           \
    _Pragma("unroll") for (int j_ = 0; j_ < 2; ++j_) {                         \
      acc[(mh)*4 + i_][(nh)*2 + j_] =                                          \
          mfma16(af[i_][0], BF[j_][0], acc[(mh)*4 + i_][(nh)*2 + j_]);         \
      acc[(mh)*4 + i_][(nh)*2 + j_] =                                          \
          mfma16(af[i_][1], BF[j_][1], acc[(mh)*4 + i_][(nh)*2 + j_]);         \
    }                                                                          \
  } while (0)
#define STG_A(db, half, t)                                                     \
  do {                                                                         \
    gload16(gA + (half)*131072 + (t)*64, &smA[db][half][w512]);                \
    gload16(gA + (half)*131072 + 65536 + (t)*64, &smA[db][half][w512 + 4096]); \
  } while (0)
#define STG_B(db, half, t)                                                     \
  do {                                                                         \
    gload16(gB + (half)*131072 + (t)*64, &smB[db][half][w512]);                \
    gload16(gB + (half)*131072 + 65536 + (t)*64, &smB[db][half][w512 + 4096]); \
  } while (0)
#define PH_OPEN                                                                \
  __builtin_amdgcn_s_barrier();                                                \
  asm volatile("s_waitcnt lgkmcnt(0)" ::: "memory");                           \
  __builtin_amdgcn_sched_barrier(0);                                           \
  __builtin_amdgcn_s_setprio(1)
#define PH_CLOSE                                                               \
  __builtin_amdgcn_s_setprio(0);                                               \
  __builtin_amdgcn_sched_barrier(0);                                           \
  __builtin_amdgcn_s_barrier();                                                \
  __builtin_amdgcn_sched_barrier(0)
#define PH_CLOSE_VM                                                            \
  __builtin_amdgcn_s_setprio(0);                                               \
  asm volatile("s_waitcnt vmcnt(2)" ::: "memory");                             \
  __builtin_amdgcn_sched_barrier(0);                                           \
  __builtin_amdgcn_s_barrier();                                                \
  __builtin_amdgcn_sched_barrier(0)

  // prologue: tile0 (4 half-tiles, db0) + tile1 A.h0 (db1); need tile0 done.
  STG_A(0, 0, 0); STG_A(0, 1, 0); STG_B(0, 0, 0); STG_B(0, 1, 0);
  STG_A(1, 0, 1);
  asm volatile("s_waitcnt vmcnt(2)" ::: "memory");
  __builtin_amdgcn_s_barrier();
  __builtin_amdgcn_sched_barrier(0);

  for (int it = 0; it < 8; ++it) {
    const int tO = 2 * it + 1;          // odd tile (db1), staged p1-p3
    const int tE2 = (2 * it + 2) & 15;  // next even tile (db0), staged p4-p7
    const int tO2 = (2 * it + 3) & 15;  // next odd tile A.h0, staged p8
    // p1: even tile, quad(0,0)
    RDA(0, 0); RDB(0, 0, bf0); STG_A(1, 1, tO);
    PH_OPEN; QUAD(0, 0, bf0); PH_CLOSE;
    // p2: quad(0,1)
    RDB(0, 1, bf1); STG_B(1, 0, tO);
    PH_OPEN; QUAD(0, 1, bf1); PH_CLOSE;
    // p3: quad(1,1)
    RDA(0, 1); STG_B(1, 1, tO);
    PH_OPEN; QUAD(1, 1, bf1); PH_CLOSE;
    // p4: quad(1,0); vmcnt(2) -> everything staged through p3 resident
    RDB(0, 0, bf0); STG_A(0, 0, tE2);
    PH_OPEN; QUAD(1, 0, bf0); PH_CLOSE_VM;
    // p5: odd tile, quad(0,0)
    RDA(1, 0); RDB(1, 0, bf0); STG_A(0, 1, tE2);
    PH_OPEN; QUAD(0, 0, bf0); PH_CLOSE;
    // p6: quad(0,1)
    RDB(1, 1, bf1); STG_B(0, 0, tE2);
    PH_OPEN; QUAD(0, 1, bf1); PH_CLOSE;
    // p7: quad(1,1)
    RDA(1, 1); STG_B(0, 1, tE2);
    PH_OPEN; QUAD(1, 1, bf1); PH_CLOSE;
    // p8: quad(1,0); vmcnt(2) -> p4-p7 stages resident for next iter
    RDB(1, 0, bf0); STG_A(1, 0, tO2);
    PH_OPEN; QUAD(1, 0, bf0); PH_CLOSE_VM;
  }
#undef RDA
#undef RDB
#undef QUAD
#undef STG_A
#undef STG_B
#undef PH_OPEN
#undef PH_CLOSE
#undef PH_CLOSE_VM

  const int which = n0 >> 10;  // 0=Q, 1=K, 2=V (uniform per block: 256 | 1024)
#pragma unroll
  for (int mf = 0; mf < 8; ++mf) {
#pragma unroll
    for (int nf = 0; nf < 4; ++nf) {
#pragma unroll
      for (int r = 0; r < 4; ++r) {
        int grow = m0 + wm * 128 + mf * 16 + g * 4 + r;  // C row
        int gcol = n0 + wn * 64 + nf * 16 + ql;          // C col
        float v = acc[mf][nf][r];
        int bb = grow >> 11, n = grow & 2047;
        int cc = gcol & 1023, h = cc >> 6, dh = cc & 63;
        size_t bh = (size_t)bb * NH + h;
        if (which == 0)
          qw[(bh * NSEQ + n) * 64 + dh] = f2bf(v * 0.18033688011112042f);
        else if (which == 1)
          kw[(bh * NSEQ + n) * 64 + dh] = f2bf(v);
        else
          vtw[(bh * 64 + dh) * NSEQ + n] = f2bf(v);
      }
    }
  }
}

// ---------------- causal flash attention (swapped-QK, log2 domain) --------
__global__ __launch_bounds__(256, 4) void attn_k(const unsigned short* __restrict__ qw,
                                                 const unsigned short* __restrict__ kw,
                                                 const unsigned short* __restrict__ vtw,
                                                 float* __restrict__ out) {
  __shared__ unsigned short smK[2][64 * 64];
  __shared__ unsigned short smV[2][64 * 64];
  __shared__ unsigned short smP[4][16 * 64];
  const int tid = threadIdx.x, w = tid >> 6, l = tid & 63;
  const int g = l >> 4, ql = l & 15;
  const int qx = (ql & 7) << 4;   // XOR swizzle for the P buffer

  const int wg = blockIdx.x;
  const int xcd = wg & 7, s = wg >> 3;   // s: 0..127
  const int bhl = s >> 5;                // local bh on this XCD
  const int s5 = s & 31;
  const int j = (s5 + 5 * bhl) & 31;     // per-bh rotation (stride 5)
  const int qt = (j & 1) ? (j >> 1) : (31 - (j >> 1));  // heavy/light interleave
  const int bh = xcd * 4 + bhl;
  const int b = bh >> 4, h = bh & 15;
  const int qbase = qt * 64;

  const unsigned short* qb = qw + (size_t)bh * NSEQ * 64;
  const unsigned short* kb = kw + (size_t)bh * NSEQ * 64;
  const unsigned short* vb = vtw + (size_t)bh * 64 * NSEQ;
  char* pl = (char*)smP[w];

  // staging: 512 16B-chunks per 64x64 tile, 2 per thread, XOR-source swizzle
  const int i0 = tid, i1 = tid + 256;
  const int r0 = i0 >> 3, c0 = (i0 & 7) ^ (r0 & 7);
  const int r1 = i1 >> 3, c1 = (i1 & 7) ^ (r1 & 7);

  // Q fragment (B-operand layout: lane holds Q[q=ql][d=g*8+j])
  const int qrow = qbase + w * 16 + ql;
  const bf16x8 qf0 = *reinterpret_cast<const bf16x8*>(qb + (size_t)qrow * 64 + g * 8);
  const bf16x8 qf1 = *reinterpret_cast<const bf16x8*>(qb + (size_t)qrow * 64 + 32 + g * 8);

  float m = -1e30f, lsum = 0.f;
  f32x4 o[4];
#pragma unroll
  for (int c = 0; c < 4; ++c) o[c] = (f32x4){0.f, 0.f, 0.f, 0.f};

#define STAGE(B, T)                                                               \
  do {                                                                            \
    gload16(kb + ((size_t)(T) * 64 + r0) * 64 + c0 * 8, smK[B] + w * 512);        \
    gload16(vb + (size_t)r0 * NSEQ + (T) * 64 + c0 * 8, smV[B] + w * 512);        \
    gload16(kb + ((size_t)(T) * 64 + r1) * 64 + c1 * 8, smK[B] + w * 512 + 2048); \
    gload16(vb + (size_t)r1 * NSEQ + (T) * 64 + c1 * 8, smV[B] + w * 512 + 2048); \
  } while (0)

  STAGE(0, 0);
  for (int t = 0; t <= qt; ++t) {
    __syncthreads();               // implicit vmcnt drain of tile-t loads
    const int cur = t & 1;
    if (t < qt) STAGE(cur ^ 1, t + 1);

    const unsigned short* K = smK[cur];
    const unsigned short* V = smV[cur];

    // S^T = K x Q^T : s[c] rows = k (c*16 + g*4 + r), col = q (ql)
    f32x4 sc4[4];
#pragma unroll
    for (int c = 0; c < 4; ++c) sc4[c] = (f32x4){0.f, 0.f, 0.f, 0.f};
    __builtin_amdgcn_s_setprio(1);
#pragma unroll
    for (int c = 0; c < 4; ++c) {
      const int krow = c * 16 + ql, sw = krow & 7;
      bf16x8 kf0 = *reinterpret_cast<const bf16x8*>(K + krow * 64 + ((g ^ sw) * 8));
      bf16x8 kf1 = *reinterpret_cast<const bf16x8*>(K + krow * 64 + (((4 + g) ^ sw) * 8));
      sc4[c] = mfma16(kf0, qf0, sc4[c]);
      sc4[c] = mfma16(kf1, qf1, sc4[c]);
    }
    __builtin_amdgcn_s_setprio(0);

    if (t == qt) {  // diagonal tile: causal mask (k_local > q_local)
      const int qloc = w * 16 + ql;
#pragma unroll
      for (int c = 0; c < 4; ++c)
#pragma unroll
        for (int r = 0; r < 4; ++r)
          if (c * 16 + g * 4 + r > qloc) sc4[c][r] = -1e30f;
    }

    // lane-local row stats (16 of 64 k per lane; finish across 4 lane-copies)
    float tmax = sc4[0][0];
#pragma unroll
    for (int c = 0; c < 4; ++c)
#pragma unroll
      for (int r = 0; r < 4; ++r) tmax = fmaxf(tmax, sc4[c][r]);
    tmax = fmaxf(tmax, __shfl_xor(tmax, 16, 64));
    tmax = fmaxf(tmax, __shfl_xor(tmax, 32, 64));

    if (!__all(tmax <= m + 8.0f)) {  // defer-max: skip rescale if bounded
      const float mn = fmaxf(m, tmax);
      const float sc = exp2g(m - mn);
      m = mn;
      lsum *= sc;
      float sco[4];
#pragma unroll
      for (int r = 0; r < 4; ++r) sco[r] = __shfl(sc, (l & 48) + g * 4 + r, 64);
#pragma unroll
      for (int c = 0; c < 4; ++c)
#pragma unroll
        for (int r = 0; r < 4; ++r) o[c][r] *= sco[r];
    }

    float rsum = 0.f;
#pragma unroll
    for (int c = 0; c < 4; ++c) {
      float p0 = exp2g(sc4[c][0] - m), p1 = exp2g(sc4[c][1] - m);
      float p2 = exp2g(sc4[c][2] - m), p3 = exp2g(sc4[c][3] - m);
      rsum += (p0 + p1) + (p2 + p3);
      unsigned int u0 = cvtpk(p0, p1), u1 = cvtpk(p2, p3);
      *reinterpret_cast<uint2*>(pl + ql * 128 + ((32 * c + 8 * g) ^ qx)) =
          make_uint2(u0, u1);
    }
    rsum += __shfl_xor(rsum, 16, 64);
    rsum += __shfl_xor(rsum, 32, 64);
    lsum += rsum;

    asm volatile("s_waitcnt lgkmcnt(0)" ::: "memory");
    __builtin_amdgcn_sched_barrier(0);

    // PV: A = P[q][k] (this wave's LDS), B = V[k][d] (from Vt tile)
    bf16x8 pf0 = *reinterpret_cast<const bf16x8*>(pl + ql * 128 + ((16 * g) ^ qx));
    bf16x8 pf1 = *reinterpret_cast<const bf16x8*>(pl + ql * 128 + ((64 + 16 * g) ^ qx));
    __builtin_amdgcn_s_setprio(1);
#pragma unroll
    for (int c = 0; c < 4; ++c) {
      const int vrow = c * 16 + ql, sw = vrow & 7;
      bf16x8 vf0 = *reinterpret_cast<const bf16x8*>(V + vrow * 64 + ((g ^ sw) * 8));
      bf16x8 vf1 = *reinterpret_cast<const bf16x8*>(V + vrow * 64 + (((4 + g) ^ sw) * 8));
      o[c] = mfma16(pf0, vf0, o[c]);
      o[c] = mfma16(pf1, vf1, o[c]);
    }
    __builtin_amdgcn_s_setprio(0);
  }
#undef STAGE

  // epilogue: o rows = q (g*4+r), cols = d (c*16+ql); normalize by row-sum
  const float linv = 1.0f / lsum;
  float lo4[4];
#pragma unroll
  for (int r = 0; r < 4; ++r) lo4[r] = __shfl(linv, (l & 48) + g * 4 + r, 64);
#pragma unroll
  for (int c = 0; c < 4; ++c) {
#pragma unroll
    for (int r = 0; r < 4; ++r) {
      const int n = qbase + w * 16 + g * 4 + r;
      const int dh = c * 16 + ql;
      out[((size_t)b * NSEQ + n) * D + h * 64 + dh] = o[c][r] * lo4[r];
    }
  }
}

extern "C" void kernel_launch(void* const* d_in, const int* in_sizes, int n_in,
                              void* d_out, int out_size, void* d_ws, size_t ws_size,
                              hipStream_t stream) {
  const float* x = (const float*)d_in[0];
  const float* W = (const float*)d_in[1];
  float* out = (float*)d_out;
  char* ws = (char*)d_ws;
  unsigned short* xb  = (unsigned short*)(ws);               // 8 MB
  unsigned short* Wt  = (unsigned short*)(ws + 8388608);     // 6 MB
  unsigned short* qw  = (unsigned short*)(ws + 14680064);    // 8 MB
  unsigned short* kw  = (unsigned short*)(ws + 23068672);    // 8 MB
  unsigned short* vtw = (unsigned short*)(ws + 31457280);    // 8 MB

  prep_k<<<7168, 256, 0, stream>>>(x, W, xb, Wt);
  qkv_gemm_k<<<dim3(16, 12), 512, 0, stream>>>(xb, Wt, qw, kw, vtw);
  attn_k<<<1024, 256, 0, stream>>>(qw, kw, vtw, out);
}

// Round 5
// 91.956 us; speedup vs baseline: 1.2568x; 1.2568x over previous
//
#include <hip/hip_runtime.h>

typedef __attribute__((ext_vector_type(8))) short bf16x8;
typedef __attribute__((ext_vector_type(4))) float f32x4;

#define DEVI static __device__ __forceinline__

namespace {
constexpr int NSEQ = 2048, NH = 16;
constexpr int D = 1024, D3 = 3072;
}

DEVI unsigned short f2bf(float f) {
  union { float f; unsigned int u; } v; v.f = f;
  unsigned int r = v.u + 0x7FFFu + ((v.u >> 16) & 1u);
  return (unsigned short)(r >> 16);
}

DEVI void gload16(const unsigned short* g, unsigned short* lds) {
  __builtin_amdgcn_global_load_lds(
      (const __attribute__((address_space(1))) unsigned int*)g,
      (__attribute__((address_space(3))) unsigned int*)lds, 16, 0, 0);
}

DEVI f32x4 mfma16(bf16x8 a, bf16x8 b, f32x4 c) {
  return __builtin_amdgcn_mfma_f32_16x16x32_bf16(a, b, c, 0, 0, 0);
}

DEVI float exp2g(float x) {
#if __has_builtin(__builtin_amdgcn_exp2f)
  return __builtin_amdgcn_exp2f(x);
#else
  return exp2f(x);
#endif
}

DEVI unsigned int cvtpk(float a, float b) {
  unsigned int r;
  asm("v_cvt_pk_bf16_f32 %0, %1, %2" : "=v"(r) : "v"(a), "v"(b));
  return r;
}

// ---------------- prep: cast x -> bf16  +  transpose/cast W -> Wt ----------
__global__ __launch_bounds__(256) void prep_k(const float* __restrict__ x,
                                              const float* __restrict__ W,
                                              unsigned short* __restrict__ xb,
                                              unsigned short* __restrict__ Wt) {
  __shared__ float t[32][33];
  const int bid = blockIdx.x;
  if (bid < 4096) {
    int i = (bid * 256 + threadIdx.x) * 4;
    float4 v = *reinterpret_cast<const float4*>(x + i);
    ushort4 o;
    o.x = f2bf(v.x); o.y = f2bf(v.y); o.z = f2bf(v.z); o.w = f2bf(v.w);
    *reinterpret_cast<ushort4*>(xb + i) = o;
  } else {
    const int b2 = bid - 4096;
    const int c0 = (b2 % 96) * 32, k0 = (b2 / 96) * 32;
    const int tx = threadIdx.x & 31, ty = threadIdx.x >> 5;  // ty 0..7
#pragma unroll
    for (int r = 0; r < 32; r += 8)
      t[ty + r][tx] = W[(size_t)(k0 + ty + r) * D3 + c0 + tx];
    __syncthreads();
#pragma unroll
    for (int r = 0; r < 32; r += 8)
      Wt[(size_t)(c0 + ty + r) * D + k0 + tx] = f2bf(t[tx][ty + r]);
  }
}

// ---------------- QKV GEMM: [4096x1024] x [1024x3072] -------------
// 128x128 tile, BK=32, 2x2 waves of 64x64, 16x16x32 bf16 MFMA.
// Two-barrier single-buffer K-loop (measured-best structure for this shape).
// Epilogue scatters: Q*(0.125*log2e) -> [B,H,N,64], K -> [B,H,N,64],
// V^T -> [B,H,64,N]
__global__ __launch_bounds__(256) void qkv_gemm_k(const unsigned short* __restrict__ xb,
                                                  const unsigned short* __restrict__ Wt,
                                                  unsigned short* __restrict__ qw,
                                                  unsigned short* __restrict__ kw,
                                                  unsigned short* __restrict__ vtw) {
  __shared__ unsigned short smA[128 * 32];
  __shared__ unsigned short smB[128 * 32];
  const int tid = threadIdx.x, w = tid >> 6, l = tid & 63;
  const int m0 = blockIdx.x * 128, n0 = blockIdx.y * 128;
  const int wm = w >> 1, wn = w & 1;

  const unsigned short* ga[2]; const unsigned short* gb[2];
  unsigned short* la[2]; unsigned short* lb[2];
#pragma unroll
  for (int i = 0; i < 2; ++i) {
    int idx = tid + i * 256;
    int row = idx >> 2;
    int blk = (idx & 3) ^ ((row >> 1) & 3);   // pre-swizzled global source
    ga[i] = xb + (size_t)(m0 + row) * D + blk * 8;
    gb[i] = Wt + (size_t)(n0 + row) * D + blk * 8;
    la[i] = smA + (w * 64 + i * 256) * 8;     // wave-uniform linear LDS dest
    lb[i] = smB + (w * 64 + i * 256) * 8;
  }

  f32x4 acc[4][4];
#pragma unroll
  for (int a = 0; a < 4; ++a)
#pragma unroll
    for (int b = 0; b < 4; ++b) acc[a][b] = (f32x4){0.f, 0.f, 0.f, 0.f};

  for (int kt = 0; kt < D / 32; ++kt) {
    __syncthreads();
#pragma unroll
    for (int i = 0; i < 2; ++i) {
      gload16(ga[i] + kt * 32, la[i]);
      gload16(gb[i] + kt * 32, lb[i]);
    }
    asm volatile("s_waitcnt vmcnt(0)" ::: "memory");
    __syncthreads();

    bf16x8 af[4], bfr[4];
#pragma unroll
    for (int a = 0; a < 4; ++a) {
      int arow = wm * 64 + a * 16 + (l & 15);
      int blk = (l >> 4) ^ ((arow >> 1) & 3);
      af[a] = *reinterpret_cast<const bf16x8*>(smA + arow * 32 + blk * 8);
    }
#pragma unroll
    for (int b = 0; b < 4; ++b) {
      int brow = wn * 64 + b * 16 + (l & 15);
      int blk = (l >> 4) ^ ((brow >> 1) & 3);
      bfr[b] = *reinterpret_cast<const bf16x8*>(smB + brow * 32 + blk * 8);
    }
#pragma unroll
    for (int a = 0; a < 4; ++a)
#pragma unroll
      for (int b = 0; b < 4; ++b)
        acc[a][b] = mfma16(af[a], bfr[b], acc[a][b]);
  }

  const int which = n0 >> 10;  // 0=Q, 1=K, 2=V (128 | 1024 so uniform per block)
#pragma unroll
  for (int a = 0; a < 4; ++a) {
#pragma unroll
    for (int b = 0; b < 4; ++b) {
#pragma unroll
      for (int r = 0; r < 4; ++r) {
        int grow = m0 + wm * 64 + a * 16 + (l >> 4) * 4 + r;  // C row
        int gcol = n0 + wn * 64 + b * 16 + (l & 15);          // C col
        float v = acc[a][b][r];
        int bb = grow >> 11, n = grow & 2047;
        int cc = gcol & 1023, h = cc >> 6, dh = cc & 63;
        size_t bh = (size_t)bb * NH + h;
        if (which == 0)
          qw[(bh * NSEQ + n) * 64 + dh] = f2bf(v * 0.18033688011112042f);
        else if (which == 1)
          kw[(bh * NSEQ + n) * 64 + dh] = f2bf(v);
        else
          vtw[(bh * 64 + dh) * NSEQ + n] = f2bf(v);
      }
    }
  }
}

// ---------------- causal flash attention (swapped-QK, log2 domain) --------
// Grid: 1024 blocks = 8 XCD x 4 bh x 32 q-tiles, balanced slot->qt map.
// Block = (bh, q-tile of 64 rows), 4 waves x 16 q-rows. S^T = mfma(K, Q):
// each lane owns one q-row -> lane-local softmax. K/V double-buffered via
// global_load_lds; ONE barrier per tile. P via per-wave XOR-swizzled LDS
// as packed bf16 (cvt_pk + ds_write_b64). T5 setprio around MFMA.
__global__ __launch_bounds__(256, 4) void attn_k(const unsigned short* __restrict__ qw,
                                                 const unsigned short* __restrict__ kw,
                                                 const unsigned short* __restrict__ vtw,
                                                 float* __restrict__ out) {
  __shared__ unsigned short smK[2][64 * 64];
  __shared__ unsigned short smV[2][64 * 64];
  __shared__ unsigned short smP[4][16 * 64];
  const int tid = threadIdx.x, w = tid >> 6, l = tid & 63;
  const int g = l >> 4, ql = l & 15;
  const int qx = (ql & 7) << 4;   // XOR swizzle for the P buffer

  const int wg = blockIdx.x;
  const int xcd = wg & 7, s = wg >> 3;   // s: 0..127
  const int bhl = s >> 5;                // local bh on this XCD
  const int s5 = s & 31;
  const int j = (s5 + 5 * bhl) & 31;     // per-bh rotation (stride 5)
  const int qt = (j & 1) ? (j >> 1) : (31 - (j >> 1));  // heavy/light interleave
  const int bh = xcd * 4 + bhl;
  const int b = bh >> 4, h = bh & 15;
  const int qbase = qt * 64;

  const unsigned short* qb = qw + (size_t)bh * NSEQ * 64;
  const unsigned short* kb = kw + (size_t)bh * NSEQ * 64;
  const unsigned short* vb = vtw + (size_t)bh * 64 * NSEQ;
  char* pl = (char*)smP[w];

  // staging: 512 16B-chunks per 64x64 tile, 2 per thread, XOR-source swizzle
  const int i0 = tid, i1 = tid + 256;
  const int r0 = i0 >> 3, c0 = (i0 & 7) ^ (r0 & 7);
  const int r1 = i1 >> 3, c1 = (i1 & 7) ^ (r1 & 7);

  // Q fragment (B-operand layout: lane holds Q[q=ql][d=g*8+j])
  const int qrow = qbase + w * 16 + ql;
  const bf16x8 qf0 = *reinterpret_cast<const bf16x8*>(qb + (size_t)qrow * 64 + g * 8);
  const bf16x8 qf1 = *reinterpret_cast<const bf16x8*>(qb + (size_t)qrow * 64 + 32 + g * 8);

  float m = -1e30f, lsum = 0.f;
  f32x4 o[4];
#pragma unroll
  for (int c = 0; c < 4; ++c) o[c] = (f32x4){0.f, 0.f, 0.f, 0.f};

#define STAGE(B, T)                                                               \
  do {                                                                            \
    gload16(kb + ((size_t)(T) * 64 + r0) * 64 + c0 * 8, smK[B] + w * 512);        \
    gload16(vb + (size_t)r0 * NSEQ + (T) * 64 + c0 * 8, smV[B] + w * 512);        \
    gload16(kb + ((size_t)(T) * 64 + r1) * 64 + c1 * 8, smK[B] + w * 512 + 2048); \
    gload16(vb + (size_t)r1 * NSEQ + (T) * 64 + c1 * 8, smV[B] + w * 512 + 2048); \
  } while (0)

  STAGE(0, 0);
  for (int t = 0; t <= qt; ++t) {
    __syncthreads();               // implicit vmcnt drain of tile-t loads
    const int cur = t & 1;
    if (t < qt) STAGE(cur ^ 1, t + 1);

    const unsigned short* K = smK[cur];
    const unsigned short* V = smV[cur];

    // S^T = K x Q^T : s[c] rows = k (c*16 + g*4 + r), col = q (ql)
    f32x4 sc4[4];
#pragma unroll
    for (int c = 0; c < 4; ++c) sc4[c] = (f32x4){0.f, 0.f, 0.f, 0.f};
    __builtin_amdgcn_s_setprio(1);
#pragma unroll
    for (int c = 0; c < 4; ++c) {
      const int krow = c * 16 + ql, sw = krow & 7;
      bf16x8 kf0 = *reinterpret_cast<const bf16x8*>(K + krow * 64 + ((g ^ sw) * 8));
      bf16x8 kf1 = *reinterpret_cast<const bf16x8*>(K + krow * 64 + (((4 + g) ^ sw) * 8));
      sc4[c] = mfma16(kf0, qf0, sc4[c]);
      sc4[c] = mfma16(kf1, qf1, sc4[c]);
    }
    __builtin_amdgcn_s_setprio(0);

    if (t == qt) {  // diagonal tile: causal mask (k_local > q_local)
      const int qloc = w * 16 + ql;
#pragma unroll
      for (int c = 0; c < 4; ++c)
#pragma unroll
        for (int r = 0; r < 4; ++r)
          if (c * 16 + g * 4 + r > qloc) sc4[c][r] = -1e30f;
    }

    // lane-local row stats (16 of 64 k per lane; finish across 4 lane-copies)
    float tmax = sc4[0][0];
#pragma unroll
    for (int c = 0; c < 4; ++c)
#pragma unroll
      for (int r = 0; r < 4; ++r) tmax = fmaxf(tmax, sc4[c][r]);
    tmax = fmaxf(tmax, __shfl_xor(tmax, 16, 64));
    tmax = fmaxf(tmax, __shfl_xor(tmax, 32, 64));

    if (!__all(tmax <= m + 8.0f)) {  // defer-max: skip rescale if bounded
      const float mn = fmaxf(m, tmax);
      const float sc = exp2g(m - mn);
      m = mn;
      lsum *= sc;
      float sco[4];
#pragma unroll
      for (int r = 0; r < 4; ++r) sco[r] = __shfl(sc, (l & 48) + g * 4 + r, 64);
#pragma unroll
      for (int c = 0; c < 4; ++c)
#pragma unroll
        for (int r = 0; r < 4; ++r) o[c][r] *= sco[r];
    }

    float rsum = 0.f;
#pragma unroll
    for (int c = 0; c < 4; ++c) {
      float p0 = exp2g(sc4[c][0] - m), p1 = exp2g(sc4[c][1] - m);
      float p2 = exp2g(sc4[c][2] - m), p3 = exp2g(sc4[c][3] - m);
      rsum += (p0 + p1) + (p2 + p3);
      unsigned int u0 = cvtpk(p0, p1), u1 = cvtpk(p2, p3);
      *reinterpret_cast<uint2*>(pl + ql * 128 + ((32 * c + 8 * g) ^ qx)) =
          make_uint2(u0, u1);
    }
    rsum += __shfl_xor(rsum, 16, 64);
    rsum += __shfl_xor(rsum, 32, 64);
    lsum += rsum;

    asm volatile("s_waitcnt lgkmcnt(0)" ::: "memory");
    __builtin_amdgcn_sched_barrier(0);

    // PV: A = P[q][k] (this wave's LDS), B = V[k][d] (from Vt tile)
    bf16x8 pf0 = *reinterpret_cast<const bf16x8*>(pl + ql * 128 + ((16 * g) ^ qx));
    bf16x8 pf1 = *reinterpret_cast<const bf16x8*>(pl + ql * 128 + ((64 + 16 * g) ^ qx));
    __builtin_amdgcn_s_setprio(1);
#pragma unroll
    for (int c = 0; c < 4; ++c) {
      const int vrow = c * 16 + ql, sw = vrow & 7;
      bf16x8 vf0 = *reinterpret_cast<const bf16x8*>(V + vrow * 64 + ((g ^ sw) * 8));
      bf16x8 vf1 = *reinterpret_cast<const bf16x8*>(V + vrow * 64 + (((4 + g) ^ sw) * 8));
      o[c] = mfma16(pf0, vf0, o[c]);
      o[c] = mfma16(pf1, vf1, o[c]);
    }
    __builtin_amdgcn_s_setprio(0);
  }
#undef STAGE

  // epilogue: o rows = q (g*4+r), cols = d (c*16+ql); normalize by row-sum
  const float linv = 1.0f / lsum;
  float lo4[4];
#pragma unroll
  for (int r = 0; r < 4; ++r) lo4[r] = __shfl(linv, (l & 48) + g * 4 + r, 64);
#pragma unroll
  for (int c = 0; c < 4; ++c) {
#pragma unroll
    for (int r = 0; r < 4; ++r) {
      const int n = qbase + w * 16 + g * 4 + r;
      const int dh = c * 16 + ql;
      out[((size_t)b * NSEQ + n) * D + h * 64 + dh] = o[c][r] * lo4[r];
    }
  }
}

extern "C" void kernel_launch(void* const* d_in, const int* in_sizes, int n_in,
                              void* d_out, int out_size, void* d_ws, size_t ws_size,
                              hipStream_t stream) {
  const float* x = (const float*)d_in[0];
  const float* W = (const float*)d_in[1];
  float* out = (float*)d_out;
  char* ws = (char*)d_ws;
  unsigned short* xb  = (unsigned short*)(ws);               // 8 MB
  unsigned short* Wt  = (unsigned short*)(ws + 8388608);     // 6 MB
  unsigned short* qw  = (unsigned short*)(ws + 14680064);    // 8 MB
  unsigned short* kw  = (unsigned short*)(ws + 23068672);    // 8 MB
  unsigned short* vtw = (unsigned short*)(ws + 31457280);    // 8 MB

  prep_k<<<7168, 256, 0, stream>>>(x, W, xb, Wt);
  qkv_gemm_k<<<dim3(32, 24), 256, 0, stream>>>(xb, Wt, qw, kw, vtw);
  attn_k<<<1024, 256, 0, stream>>>(qw, kw, vtw, out);
}

// Round 6
// 89.953 us; speedup vs baseline: 1.2848x; 1.0223x over previous
//
#include <hip/hip_runtime.h>

typedef __attribute__((ext_vector_type(8))) short bf16x8;
typedef __attribute__((ext_vector_type(4))) float f32x4;

#define DEVI static __device__ __forceinline__

namespace {
constexpr int NSEQ = 2048, NH = 16;
constexpr int D = 1024, D3 = 3072;
}

DEVI unsigned short f2bf(float f) {
  union { float f; unsigned int u; } v; v.f = f;
  unsigned int r = v.u + 0x7FFFu + ((v.u >> 16) & 1u);
  return (unsigned short)(r >> 16);
}

DEVI void gload16(const unsigned short* g, unsigned short* lds) {
  __builtin_amdgcn_global_load_lds(
      (const __attribute__((address_space(1))) unsigned int*)g,
      (__attribute__((address_space(3))) unsigned int*)lds, 16, 0, 0);
}

DEVI f32x4 mfma16(bf16x8 a, bf16x8 b, f32x4 c) {
  return __builtin_amdgcn_mfma_f32_16x16x32_bf16(a, b, c, 0, 0, 0);
}

DEVI float exp2g(float x) {
#if __has_builtin(__builtin_amdgcn_exp2f)
  return __builtin_amdgcn_exp2f(x);
#else
  return exp2f(x);
#endif
}

DEVI unsigned int cvtpk(float a, float b) {
  unsigned int r;
  asm("v_cvt_pk_bf16_f32 %0, %1, %2" : "=v"(r) : "v"(a), "v"(b));
  return r;
}

// ---------------- prep: cast x -> bf16  +  transpose/cast W -> Wt ----------
__global__ __launch_bounds__(256) void prep_k(const float* __restrict__ x,
                                              const float* __restrict__ W,
                                              unsigned short* __restrict__ xb,
                                              unsigned short* __restrict__ Wt) {
  __shared__ float t[32][33];
  const int bid = blockIdx.x;
  if (bid < 4096) {
    int i = (bid * 256 + threadIdx.x) * 4;
    float4 v = *reinterpret_cast<const float4*>(x + i);
    ushort4 o;
    o.x = f2bf(v.x); o.y = f2bf(v.y); o.z = f2bf(v.z); o.w = f2bf(v.w);
    *reinterpret_cast<ushort4*>(xb + i) = o;
  } else {
    const int b2 = bid - 4096;
    const int c0 = (b2 % 96) * 32, k0 = (b2 / 96) * 32;
    const int tx = threadIdx.x & 31, ty = threadIdx.x >> 5;  // ty 0..7
#pragma unroll
    for (int r = 0; r < 32; r += 8)
      t[ty + r][tx] = W[(size_t)(k0 + ty + r) * D3 + c0 + tx];
    __syncthreads();
#pragma unroll
    for (int r = 0; r < 32; r += 8)
      Wt[(size_t)(c0 + ty + r) * D + k0 + tx] = f2bf(t[tx][ty + r]);
  }
}

// ---------------- QKV GEMM: [4096x1024] x [1024x3072] -------------
// 128x128 tile, BK=32, 2x2 waves of 64x64, 16x16x32 bf16 MFMA.
// Two-barrier single-buffer K-loop (measured-best structure for this shape).
__global__ __launch_bounds__(256) void qkv_gemm_k(const unsigned short* __restrict__ xb,
                                                  const unsigned short* __restrict__ Wt,
                                                  unsigned short* __restrict__ qw,
                                                  unsigned short* __restrict__ kw,
                                                  unsigned short* __restrict__ vtw) {
  __shared__ unsigned short smA[128 * 32];
  __shared__ unsigned short smB[128 * 32];
  const int tid = threadIdx.x, w = tid >> 6, l = tid & 63;
  const int m0 = blockIdx.x * 128, n0 = blockIdx.y * 128;
  const int wm = w >> 1, wn = w & 1;

  const unsigned short* ga[2]; const unsigned short* gb[2];
  unsigned short* la[2]; unsigned short* lb[2];
#pragma unroll
  for (int i = 0; i < 2; ++i) {
    int idx = tid + i * 256;
    int row = idx >> 2;
    int blk = (idx & 3) ^ ((row >> 1) & 3);   // pre-swizzled global source
    ga[i] = xb + (size_t)(m0 + row) * D + blk * 8;
    gb[i] = Wt + (size_t)(n0 + row) * D + blk * 8;
    la[i] = smA + (w * 64 + i * 256) * 8;     // wave-uniform linear LDS dest
    lb[i] = smB + (w * 64 + i * 256) * 8;
  }

  f32x4 acc[4][4];
#pragma unroll
  for (int a = 0; a < 4; ++a)
#pragma unroll
    for (int b = 0; b < 4; ++b) acc[a][b] = (f32x4){0.f, 0.f, 0.f, 0.f};

  for (int kt = 0; kt < D / 32; ++kt) {
    __syncthreads();
#pragma unroll
    for (int i = 0; i < 2; ++i) {
      gload16(ga[i] + kt * 32, la[i]);
      gload16(gb[i] + kt * 32, lb[i]);
    }
    asm volatile("s_waitcnt vmcnt(0)" ::: "memory");
    __syncthreads();

    bf16x8 af[4], bfr[4];
#pragma unroll
    for (int a = 0; a < 4; ++a) {
      int arow = wm * 64 + a * 16 + (l & 15);
      int blk = (l >> 4) ^ ((arow >> 1) & 3);
      af[a] = *reinterpret_cast<const bf16x8*>(smA + arow * 32 + blk * 8);
    }
#pragma unroll
    for (int b = 0; b < 4; ++b) {
      int brow = wn * 64 + b * 16 + (l & 15);
      int blk = (l >> 4) ^ ((brow >> 1) & 3);
      bfr[b] = *reinterpret_cast<const bf16x8*>(smB + brow * 32 + blk * 8);
    }
#pragma unroll
    for (int a = 0; a < 4; ++a)
#pragma unroll
      for (int b = 0; b < 4; ++b)
        acc[a][b] = mfma16(af[a], bfr[b], acc[a][b]);
  }

  const int which = n0 >> 10;  // 0=Q, 1=K, 2=V (128 | 1024 so uniform per block)
#pragma unroll
  for (int a = 0; a < 4; ++a) {
#pragma unroll
    for (int b = 0; b < 4; ++b) {
#pragma unroll
      for (int r = 0; r < 4; ++r) {
        int grow = m0 + wm * 64 + a * 16 + (l >> 4) * 4 + r;  // C row
        int gcol = n0 + wn * 64 + b * 16 + (l & 15);          // C col
        float v = acc[a][b][r];
        int bb = grow >> 11, n = grow & 2047;
        int cc = gcol & 1023, h = cc >> 6, dh = cc & 63;
        size_t bh = (size_t)bb * NH + h;
        if (which == 0)
          qw[(bh * NSEQ + n) * 64 + dh] = f2bf(v * 0.18033688011112042f);
        else if (which == 1)
          kw[(bh * NSEQ + n) * 64 + dh] = f2bf(v);
        else
          vtw[(bh * 64 + dh) * NSEQ + n] = f2bf(v);
      }
    }
  }
}

// ---------------- causal flash attention (swapped-QK, log2 domain) --------
// Grid: 512 blocks = 8 XCD x 4 bh x 16 pairs. Each block processes q-tile
// pair {31-j, j} sequentially = EXACTLY 33 k-tiles -> every block uniform,
// every CU uniform (2 blocks/CU, 8 waves). 4 waves x 16 q-rows per q-tile.
// S^T = mfma(K, Q): lane-local softmax. K/V double-buffered gload_lds, one
// barrier per tile. P via per-wave XOR-swizzled LDS (cvt_pk). T5 setprio.
__global__ __launch_bounds__(256, 4) void attn_k(const unsigned short* __restrict__ qw,
                                                 const unsigned short* __restrict__ kw,
                                                 const unsigned short* __restrict__ vtw,
                                                 float* __restrict__ out) {
  __shared__ unsigned short smK[2][64 * 64];
  __shared__ unsigned short smV[2][64 * 64];
  __shared__ unsigned short smP[4][16 * 64];
  const int tid = threadIdx.x, w = tid >> 6, l = tid & 63;
  const int g = l >> 4, ql = l & 15;
  const int qx = (ql & 7) << 4;   // XOR swizzle for the P buffer

  const int wg = blockIdx.x;           // 512 blocks
  const int xcd = wg & 7, rest = wg >> 3;  // rest: 0..63
  const int bhl = rest >> 4;           // 0..3 local bh on this XCD
  const int j = rest & 15;             // pair index
  const int bh = xcd * 4 + bhl;
  const int b = bh >> 4, h = bh & 15;

  const unsigned short* qb = qw + (size_t)bh * NSEQ * 64;
  const unsigned short* kb = kw + (size_t)bh * NSEQ * 64;
  const unsigned short* vb = vtw + (size_t)bh * 64 * NSEQ;
  char* pl = (char*)smP[w];

  // staging: 512 16B-chunks per 64x64 tile, 2 per thread, XOR-source swizzle
  const int i0 = tid, i1 = tid + 256;
  const int r0 = i0 >> 3, c0 = (i0 & 7) ^ (r0 & 7);
  const int r1 = i1 >> 3, c1 = (i1 & 7) ^ (r1 & 7);

#define STAGE(B, T)                                                               \
  do {                                                                            \
    gload16(kb + ((size_t)(T) * 64 + r0) * 64 + c0 * 8, smK[B] + w * 512);        \
    gload16(vb + (size_t)r0 * NSEQ + (T) * 64 + c0 * 8, smV[B] + w * 512);        \
    gload16(kb + ((size_t)(T) * 64 + r1) * 64 + c1 * 8, smK[B] + w * 512 + 2048); \
    gload16(vb + (size_t)r1 * NSEQ + (T) * 64 + c1 * 8, smV[B] + w * 512 + 2048); \
  } while (0)

  for (int seg = 0; seg < 2; ++seg) {
    const int qt = seg ? j : (31 - j);   // heavy q-tile first
    const int qbase = qt * 64;

    // Q fragment (B-operand layout: lane holds Q[q=ql][d=g*8+jj])
    const int qrow = qbase + w * 16 + ql;
    const bf16x8 qf0 = *reinterpret_cast<const bf16x8*>(qb + (size_t)qrow * 64 + g * 8);
    const bf16x8 qf1 = *reinterpret_cast<const bf16x8*>(qb + (size_t)qrow * 64 + 32 + g * 8);

    float m = -1e30f, lsum = 0.f;
    f32x4 o[4];
#pragma unroll
    for (int c = 0; c < 4; ++c) o[c] = (f32x4){0.f, 0.f, 0.f, 0.f};

    STAGE(0, 0);
    for (int t = 0; t <= qt; ++t) {
      __syncthreads();               // implicit vmcnt drain of tile-t loads
      const int cur = t & 1;
      if (t < qt) STAGE(cur ^ 1, t + 1);

      const unsigned short* K = smK[cur];
      const unsigned short* V = smV[cur];

      // S^T = K x Q^T : sc4[c] rows = k (c*16 + g*4 + r), col = q (ql)
      f32x4 sc4[4];
#pragma unroll
      for (int c = 0; c < 4; ++c) sc4[c] = (f32x4){0.f, 0.f, 0.f, 0.f};
      __builtin_amdgcn_s_setprio(1);
#pragma unroll
      for (int c = 0; c < 4; ++c) {
        const int krow = c * 16 + ql, sw = krow & 7;
        bf16x8 kf0 = *reinterpret_cast<const bf16x8*>(K + krow * 64 + ((g ^ sw) * 8));
        bf16x8 kf1 = *reinterpret_cast<const bf16x8*>(K + krow * 64 + (((4 + g) ^ sw) * 8));
        sc4[c] = mfma16(kf0, qf0, sc4[c]);
        sc4[c] = mfma16(kf1, qf1, sc4[c]);
      }
      __builtin_amdgcn_s_setprio(0);

      if (t == qt) {  // diagonal tile: causal mask (k_local > q_local)
        const int qloc = w * 16 + ql;
#pragma unroll
        for (int c = 0; c < 4; ++c)
#pragma unroll
          for (int r = 0; r < 4; ++r)
            if (c * 16 + g * 4 + r > qloc) sc4[c][r] = -1e30f;
      }

      // lane-local row stats (16 of 64 k per lane; finish across 4 copies)
      float tmax = sc4[0][0];
#pragma unroll
      for (int c = 0; c < 4; ++c)
#pragma unroll
        for (int r = 0; r < 4; ++r) tmax = fmaxf(tmax, sc4[c][r]);
      tmax = fmaxf(tmax, __shfl_xor(tmax, 16, 64));
      tmax = fmaxf(tmax, __shfl_xor(tmax, 32, 64));

      if (!__all(tmax <= m + 8.0f)) {  // defer-max: skip rescale if bounded
        const float mn = fmaxf(m, tmax);
        const float sc = exp2g(m - mn);
        m = mn;
        lsum *= sc;
        float sco[4];
#pragma unroll
        for (int r = 0; r < 4; ++r) sco[r] = __shfl(sc, (l & 48) + g * 4 + r, 64);
#pragma unroll
        for (int c = 0; c < 4; ++c)
#pragma unroll
          for (int r = 0; r < 4; ++r) o[c][r] *= sco[r];
      }

      float rsum = 0.f;
#pragma unroll
      for (int c = 0; c < 4; ++c) {
        float p0 = exp2g(sc4[c][0] - m), p1 = exp2g(sc4[c][1] - m);
        float p2 = exp2g(sc4[c][2] - m), p3 = exp2g(sc4[c][3] - m);
        rsum += (p0 + p1) + (p2 + p3);
        unsigned int u0 = cvtpk(p0, p1), u1 = cvtpk(p2, p3);
        *reinterpret_cast<uint2*>(pl + ql * 128 + ((32 * c + 8 * g) ^ qx)) =
            make_uint2(u0, u1);
      }
      rsum += __shfl_xor(rsum, 16, 64);
      rsum += __shfl_xor(rsum, 32, 64);
      lsum += rsum;

      asm volatile("s_waitcnt lgkmcnt(0)" ::: "memory");
      __builtin_amdgcn_sched_barrier(0);

      // PV: A = P[q][k] (this wave's LDS), B = V[k][d] (from Vt tile)
      bf16x8 pf0 = *reinterpret_cast<const bf16x8*>(pl + ql * 128 + ((16 * g) ^ qx));
      bf16x8 pf1 = *reinterpret_cast<const bf16x8*>(pl + ql * 128 + ((64 + 16 * g) ^ qx));
      __builtin_amdgcn_s_setprio(1);
#pragma unroll
      for (int c = 0; c < 4; ++c) {
        const int vrow = c * 16 + ql, sw = vrow & 7;
        bf16x8 vf0 = *reinterpret_cast<const bf16x8*>(V + vrow * 64 + ((g ^ sw) * 8));
        bf16x8 vf1 = *reinterpret_cast<const bf16x8*>(V + vrow * 64 + (((4 + g) ^ sw) * 8));
        o[c] = mfma16(pf0, vf0, o[c]);
        o[c] = mfma16(pf1, vf1, o[c]);
      }
      __builtin_amdgcn_s_setprio(0);
    }

    // epilogue: o rows = q (g*4+r), cols = d (c*16+ql); normalize by row-sum
    const float linv = 1.0f / lsum;
    float lo4[4];
#pragma unroll
    for (int r = 0; r < 4; ++r) lo4[r] = __shfl(linv, (l & 48) + g * 4 + r, 64);
#pragma unroll
    for (int c = 0; c < 4; ++c) {
#pragma unroll
      for (int r = 0; r < 4; ++r) {
        const int n = qbase + w * 16 + g * 4 + r;
        const int dh = c * 16 + ql;
        out[((size_t)b * NSEQ + n) * D + h * 64 + dh] = o[c][r] * lo4[r];
      }
    }
    __syncthreads();   // protect LDS buffers before seg1 restages
  }
#undef STAGE
}

extern "C" void kernel_launch(void* const* d_in, const int* in_sizes, int n_in,
                              void* d_out, int out_size, void* d_ws, size_t ws_size,
                              hipStream_t stream) {
  const float* x = (const float*)d_in[0];
  const float* W = (const float*)d_in[1];
  float* out = (float*)d_out;
  char* ws = (char*)d_ws;
  unsigned short* xb  = (unsigned short*)(ws);               // 8 MB
  unsigned short* Wt  = (unsigned short*)(ws + 8388608);     // 6 MB
  unsigned short* qw  = (unsigned short*)(ws + 14680064);    // 8 MB
  unsigned short* kw  = (unsigned short*)(ws + 23068672);    // 8 MB
  unsigned short* vtw = (unsigned short*)(ws + 31457280);    // 8 MB

  prep_k<<<7168, 256, 0, stream>>>(x, W, xb, Wt);
  qkv_gemm_k<<<dim3(32, 24), 256, 0, stream>>>(xb, Wt, qw, kw, vtw);
  attn_k<<<512, 256, 0, stream>>>(qw, kw, vtw, out);
}